// Round 1
// baseline (105.737 us; speedup 1.0000x reference)
//
#include <hip/hip_runtime.h>

#define SLEN 4096
#define DDIM 128
#define BATCH 4
#define QB 64
#define NQB (SLEN / QB)   // 64 q-blocks per batch
#define NW 8              // waves per attn block
#define SCALE 0.08838834764831845f  // 1/sqrt(128)

typedef __bf16 v8bf __attribute__((ext_vector_type(8)));
typedef float f32x4 __attribute__((ext_vector_type(4)));

__device__ __forceinline__ f32x4 mfma16(v8bf a, v8bf b, f32x4 c) {
  return __builtin_amdgcn_mfma_f32_16x16x32_bf16(a, b, c, 0, 0, 0);
}

// ---------------------------------------------------------------------------
// k0: pack Wq|Wk columns into MFMA B-fragment layout, bf16.
// Wt[((ct*4+hs)*64 + lane)*8 + i] = W[h = hs*32 + (lane>>4)*8 + i][col = (ct&7)*16 + (lane&15)]
__global__ __launch_bounds__(256) void k0_wt(const float* __restrict__ Wq,
                                             const float* __restrict__ Wk,
                                             __bf16* __restrict__ Wt) {
  int idx = blockIdx.x * 256 + threadIdx.x;   // 0..4095
  int ct = idx >> 8;
  int hs = (idx >> 6) & 3;
  int l  = idx & 63;
  int col = ((ct & 7) << 4) + (l & 15);
  const float* W = (ct < 8) ? Wq : Wk;
  int hbase = hs * 32 + (l >> 4) * 8;
  __bf16* dst = Wt + (size_t)idx * 8;
  for (int i = 0; i < 8; ++i)
    dst[i] = (__bf16)W[(hbase + i) * DDIM + col];
}

// ---------------------------------------------------------------------------
// k1: projections Q = x@Wq + bq, K = x@Wk + bk  -> bf16, via MFMA.
// Block: 64 rows (4 waves x 16 rows), 256 output cols (8 Q-tiles + 8 K-tiles).
__global__ __launch_bounds__(256) void k1_proj(const float* __restrict__ x,
                                               const __bf16* __restrict__ Wt,
                                               const float* __restrict__ bq,
                                               const float* __restrict__ bk,
                                               __bf16* __restrict__ Qb,
                                               __bf16* __restrict__ Kb) {
  int wave = threadIdx.x >> 6, lane = threadIdx.x & 63;
  int lr = lane & 15, lg = lane >> 4;
  int r0 = blockIdx.x * 64 + wave * 16;      // flat row over B*S
  const float* xrow = x + (size_t)(r0 + lr) * DDIM;

  v8bf xf[4];
  for (int hs = 0; hs < 4; ++hs) {
    float4 a = *reinterpret_cast<const float4*>(xrow + hs * 32 + lg * 8);
    float4 c = *reinterpret_cast<const float4*>(xrow + hs * 32 + lg * 8 + 4);
    v8bf t;
    t[0] = (__bf16)a.x; t[1] = (__bf16)a.y; t[2] = (__bf16)a.z; t[3] = (__bf16)a.w;
    t[4] = (__bf16)c.x; t[5] = (__bf16)c.y; t[6] = (__bf16)c.z; t[7] = (__bf16)c.w;
    xf[hs] = t;
  }

  for (int ct = 0; ct < 16; ++ct) {
    f32x4 acc = {0.f, 0.f, 0.f, 0.f};
    for (int hs = 0; hs < 4; ++hs) {
      v8bf wf = *reinterpret_cast<const v8bf*>(Wt + ((size_t)(ct * 4 + hs) * 64 + lane) * 8);
      acc = mfma16(xf[hs], wf, acc);
    }
    int col = ((ct & 7) << 4) + lr;
    float bias = (ct < 8) ? bq[col] : bk[col];
    __bf16* dst = (ct < 8) ? Qb : Kb;
    for (int j = 0; j < 4; ++j) {
      int row = r0 + lg * 4 + j;
      dst[(size_t)row * DDIM + col] = (__bf16)(acc[j] + bias);
    }
  }
}

// ---------------------------------------------------------------------------
// k2: per (batch, 64-row q-block): loop1 computes per-row Z = sum_k exp(s),
// loop2 recomputes exp(s) and accumulates column sums w[k] = sum_q exp/Z.
// 8 waves split the k-space (wave w owns k-tiles t % 8 == w) -> no duplication,
// deterministic disjoint writes to wpart.
__global__ __launch_bounds__(512) void k2_attn(const __bf16* __restrict__ Qb,
                                               const __bf16* __restrict__ Kb,
                                               float* __restrict__ wpart) {
  int b = blockIdx.y;
  int qblk = blockIdx.x;
  int wave = threadIdx.x >> 6, lane = threadIdx.x & 63;
  int lr = lane & 15, lg = lane >> 4;

  const __bf16* Qbase = Qb + ((size_t)b * SLEN + qblk * QB) * DDIM;
  const __bf16* Kbase = Kb + (size_t)b * SLEN * DDIM;

  // Q fragments for all 4 q-subtiles (rows qs*16 + lr), held for both loops
  v8bf qf[4][4];
  for (int qs = 0; qs < 4; ++qs)
    for (int hs = 0; hs < 4; ++hs)
      qf[qs][hs] = *reinterpret_cast<const v8bf*>(Qbase + (size_t)(qs * 16 + lr) * DDIM + hs * 32 + lg * 8);

  __shared__ float zred[NW][QB];
  __shared__ float invZ[QB];

  float zacc[4][4];
  for (int qs = 0; qs < 4; ++qs)
    for (int j = 0; j < 4; ++j) zacc[qs][j] = 0.f;

  // ---- loop 1: Z per q-row ----
  for (int t = wave; t < SLEN / 16; t += NW) {
    const __bf16* krow = Kbase + (size_t)(t * 16 + lr) * DDIM + lg * 8;
    v8bf kf[4];
    for (int hs = 0; hs < 4; ++hs)
      kf[hs] = *reinterpret_cast<const v8bf*>(krow + hs * 32);
    for (int qs = 0; qs < 4; ++qs) {
      f32x4 acc = {0.f, 0.f, 0.f, 0.f};
      for (int hs = 0; hs < 4; ++hs) acc = mfma16(qf[qs][hs], kf[hs], acc);
      for (int j = 0; j < 4; ++j)
        zacc[qs][j] += __expf(acc[j] * SCALE);
    }
  }
  // reduce partial Z over the 16 lanes (lr) holding different k columns
  for (int qs = 0; qs < 4; ++qs)
    for (int j = 0; j < 4; ++j) {
      float z = zacc[qs][j];
      z += __shfl_xor(z, 1);
      z += __shfl_xor(z, 2);
      z += __shfl_xor(z, 4);
      z += __shfl_xor(z, 8);
      if (lr == 0) zred[wave][qs * 16 + lg * 4 + j] = z;
    }
  __syncthreads();
  if (threadIdx.x < QB) {
    float z = 0.f;
    for (int w = 0; w < NW; ++w) z += zred[w][threadIdx.x];
    invZ[threadIdx.x] = 1.0f / z;
  }
  __syncthreads();

  float iz[4][4];
  for (int qs = 0; qs < 4; ++qs)
    for (int j = 0; j < 4; ++j)
      iz[qs][j] = invZ[qs * 16 + lg * 4 + j];

  // ---- loop 2: w[k] = sum_q exp(s)/Z ----
  float* wrow = wpart + ((size_t)b * NQB + qblk) * SLEN;
  for (int t = wave; t < SLEN / 16; t += NW) {
    const __bf16* krow = Kbase + (size_t)(t * 16 + lr) * DDIM + lg * 8;
    v8bf kf[4];
    for (int hs = 0; hs < 4; ++hs)
      kf[hs] = *reinterpret_cast<const v8bf*>(krow + hs * 32);
    float wk = 0.f;
    for (int qs = 0; qs < 4; ++qs) {
      f32x4 acc = {0.f, 0.f, 0.f, 0.f};
      for (int hs = 0; hs < 4; ++hs) acc = mfma16(qf[qs][hs], kf[hs], acc);
      for (int j = 0; j < 4; ++j)
        wk += __expf(acc[j] * SCALE) * iz[qs][j];
    }
    wk += __shfl_xor(wk, 16);
    wk += __shfl_xor(wk, 32);
    if (lg == 0) wrow[t * 16 + lr] = wk;   // disjoint across waves/tiles
  }
}

// ---------------------------------------------------------------------------
// k3: wsum[b,k] = sum over the 64 q-blocks of wpart
__global__ __launch_bounds__(256) void k3_wsum(const float* __restrict__ wpart,
                                               float* __restrict__ wsum) {
  int b = blockIdx.y;
  int k = blockIdx.x * 256 + threadIdx.x;
  const float* p = wpart + (size_t)b * NQB * SLEN + k;
  float s = 0.f;
  for (int j = 0; j < NQB; ++j) s += p[(size_t)j * SLEN];
  wsum[b * SLEN + k] = s;
}

// ---------------------------------------------------------------------------
// k4: upart[b,c,d] = sum over k-chunk c of wsum[b,k] * x[b,k,d]
__global__ __launch_bounds__(128) void k4_u(const float* __restrict__ x,
                                            const float* __restrict__ wsum,
                                            float* __restrict__ upart) {
  int b = blockIdx.y, c = blockIdx.x, d = threadIdx.x;
  const float* xb = x + (size_t)b * SLEN * DDIM;
  const float* wb = wsum + b * SLEN;
  float acc = 0.f;
  for (int kk = 0; kk < 128; ++kk) {
    int k = c * 128 + kk;
    acc += wb[k] * xb[(size_t)k * DDIM + d];
  }
  upart[((size_t)b * 32 + c) * DDIM + d] = acc;
}

// ---------------------------------------------------------------------------
// k5: out[b,d] = (1/S) * (u[b,:] @ Wv[:,d]) + bv[d]
__global__ __launch_bounds__(128) void k5_out(const float* __restrict__ upart,
                                              const float* __restrict__ Wv,
                                              const float* __restrict__ bv,
                                              float* __restrict__ out) {
  int b = blockIdx.x, d = threadIdx.x;
  __shared__ float u[DDIM];
  float s = 0.f;
  for (int c = 0; c < 32; ++c) s += upart[((size_t)b * 32 + c) * DDIM + d];
  u[d] = s;
  __syncthreads();
  float acc = 0.f;
  for (int dp = 0; dp < DDIM; ++dp) acc += u[dp] * Wv[(size_t)dp * DDIM + d];
  out[b * DDIM + d] = acc * (1.0f / SLEN) + bv[d];
}

// ---------------------------------------------------------------------------
extern "C" void kernel_launch(void* const* d_in, const int* in_sizes, int n_in,
                              void* d_out, int out_size, void* d_ws, size_t ws_size,
                              hipStream_t stream) {
  const float* x  = (const float*)d_in[0];
  const float* Wq = (const float*)d_in[1];
  const float* bq = (const float*)d_in[2];
  const float* Wk = (const float*)d_in[3];
  const float* bk = (const float*)d_in[4];
  const float* Wv = (const float*)d_in[5];
  const float* bv = (const float*)d_in[6];
  float* out = (float*)d_out;

  char* ws = (char*)d_ws;
  __bf16* Qb   = (__bf16*)(ws);                                   // 4 MB
  __bf16* Kb   = (__bf16*)(ws + (4u << 20));                      // 4 MB
  __bf16* Wt   = (__bf16*)(ws + (8u << 20));                      // 64 KB
  float*  wpart = (float*)(ws + (8u << 20) + (64u << 10));        // 4 MB
  float*  wsum  = (float*)(ws + (12u << 20) + (64u << 10));       // 64 KB
  float*  upart = (float*)(ws + (12u << 20) + (128u << 10));      // 16 KB

  k0_wt  <<<16, 256, 0, stream>>>(Wq, Wk, Wt);
  k1_proj<<<256, 256, 0, stream>>>(x, Wt, bq, bk, Qb, Kb);
  k2_attn<<<dim3(NQB, BATCH), 512, 0, stream>>>(Qb, Kb, wpart);
  k3_wsum<<<dim3(16, BATCH), 256, 0, stream>>>(wpart, wsum);
  k4_u   <<<dim3(32, BATCH), 128, 0, stream>>>(x, wsum, upart);
  k5_out <<<BATCH, 128, 0, stream>>>(upart, Wv, bv, out);
}